// Round 1
// baseline (493.443 us; speedup 1.0000x reference)
//
#include <hip/hip_runtime.h>
#include <math.h>

// 10-layer MLP over 2M rows, fp32, one thread per row.
// Weights are wave-uniform -> compiler emits scalar loads (s_load) and
// v_fma_f32 with SGPR weight operand: near-pure FMA issue stream.
// Activations live in registers via full unroll with compile-time dims.

__device__ __forceinline__ float swish_f(float a) {
    // a * sigmoid(a) = a / (1 + exp(-a)); fast exp2-based exp + fast rcp.
    float e = __expf(-a);
    return a * __builtin_amdgcn_rcpf(1.0f + e);
}

template <int DIN, int DOUT>
__device__ __forceinline__ void linear_layer(const float* __restrict__ W,
                                             const float* __restrict__ b,
                                             const float (&in)[DIN],
                                             float (&out)[DOUT]) {
#pragma unroll
    for (int j = 0; j < DOUT; ++j) {
        float acc = b[j];
#pragma unroll
        for (int k = 0; k < DIN; ++k) {
            acc = fmaf(W[j * DIN + k], in[k], acc);
        }
        out[j] = acc;
    }
}

template <int N>
__device__ __forceinline__ void swish_vec(float (&h)[N]) {
#pragma unroll
    for (int j = 0; j < N; ++j) h[j] = swish_f(h[j]);
}

__global__ __launch_bounds__(256) void longnet_mlp_kernel(
    const float* __restrict__ x,
    const float* __restrict__ W0, const float* __restrict__ b0,
    const float* __restrict__ W1, const float* __restrict__ b1,
    const float* __restrict__ W2, const float* __restrict__ b2,
    const float* __restrict__ W3, const float* __restrict__ b3,
    const float* __restrict__ W4, const float* __restrict__ b4,
    const float* __restrict__ W5, const float* __restrict__ b5,
    const float* __restrict__ W6, const float* __restrict__ b6,
    const float* __restrict__ W7, const float* __restrict__ b7,
    const float* __restrict__ W8, const float* __restrict__ b8,
    const float* __restrict__ W9, const float* __restrict__ b9,
    float* __restrict__ out, int n) {
    const int row = blockIdx.x * blockDim.x + threadIdx.x;
    if (row >= n) return;

    float h0[11];
#pragma unroll
    for (int k = 0; k < 11; ++k) h0[k] = x[row * 11 + k];

    float h1[20];
    linear_layer<11, 20>(W0, b0, h0, h1);
    swish_vec(h1);
    float h2[20];
    linear_layer<20, 20>(W1, b1, h1, h2);
    swish_vec(h2);
    float h3[30];
    linear_layer<20, 30>(W2, b2, h2, h3);
    swish_vec(h3);
    float h4[30];
    linear_layer<30, 30>(W3, b3, h3, h4);
    swish_vec(h4);
    float h5[40];
    linear_layer<30, 40>(W4, b4, h4, h5);
    swish_vec(h5);
    float h6[40];
    linear_layer<40, 40>(W5, b5, h5, h6);
    swish_vec(h6);
    float h7[40];
    linear_layer<40, 40>(W6, b6, h6, h7);
    swish_vec(h7);
    float h8[20];
    linear_layer<40, 20>(W7, b7, h7, h8);
    swish_vec(h8);
    float h9[10];
    linear_layer<20, 10>(W8, b8, h8, h9);
    swish_vec(h9);
    float h10[1];
    linear_layer<10, 1>(W9, b9, h9, h10);

    out[row] = fmaxf(h10[0], 0.0f);
}

extern "C" void kernel_launch(void* const* d_in, const int* in_sizes, int n_in,
                              void* d_out, int out_size, void* d_ws, size_t ws_size,
                              hipStream_t stream) {
    const float* x = (const float*)d_in[0];
    const float* W0 = (const float*)d_in[1];
    const float* b0 = (const float*)d_in[2];
    const float* W1 = (const float*)d_in[3];
    const float* b1 = (const float*)d_in[4];
    const float* W2 = (const float*)d_in[5];
    const float* b2 = (const float*)d_in[6];
    const float* W3 = (const float*)d_in[7];
    const float* b3 = (const float*)d_in[8];
    const float* W4 = (const float*)d_in[9];
    const float* b4 = (const float*)d_in[10];
    const float* W5 = (const float*)d_in[11];
    const float* b5 = (const float*)d_in[12];
    const float* W6 = (const float*)d_in[13];
    const float* b6 = (const float*)d_in[14];
    const float* W7 = (const float*)d_in[15];
    const float* b7 = (const float*)d_in[16];
    const float* W8 = (const float*)d_in[17];
    const float* b8 = (const float*)d_in[18];
    const float* W9 = (const float*)d_in[19];
    const float* b9 = (const float*)d_in[20];
    float* out = (float*)d_out;

    const int n = in_sizes[0] / 11;  // 2,000,000 rows
    const int block = 256;
    const int grid = (n + block - 1) / block;

    longnet_mlp_kernel<<<grid, block, 0, stream>>>(
        x, W0, b0, W1, b1, W2, b2, W3, b3, W4, b4, W5, b5, W6, b6, W7, b7, W8,
        b8, W9, b9, out, n);
}

// Round 2
// 493.433 us; speedup vs baseline: 1.0000x; 1.0000x over previous
//
#include <hip/hip_runtime.h>
#include <math.h>

// 10-layer MLP over 2M rows, fp32, one thread per row.
// Weights are wave-uniform -> compiler emits scalar loads (s_load) and
// v_fma_f32 with SGPR weight operand: near-pure FMA issue stream.
// Activations live in registers via full unroll with compile-time dims.
//
// R2 change: __launch_bounds__(256, 4) -> 128-VGPR cap (was: compiler chose
// 44 VGPRs for occupancy and spilled ~80-100 live activations through
// v_accvgpr moves, inflating VALU issue ~2.7x over the FMA floor).

__device__ __forceinline__ float swish_f(float a) {
    // a * sigmoid(a) = a / (1 + exp(-a)); fast exp2-based exp + fast rcp.
    float e = __expf(-a);
    return a * __builtin_amdgcn_rcpf(1.0f + e);
}

template <int DIN, int DOUT>
__device__ __forceinline__ void linear_layer(const float* __restrict__ W,
                                             const float* __restrict__ b,
                                             const float (&in)[DIN],
                                             float (&out)[DOUT]) {
#pragma unroll
    for (int j = 0; j < DOUT; ++j) {
        float acc = b[j];
#pragma unroll
        for (int k = 0; k < DIN; ++k) {
            acc = fmaf(W[j * DIN + k], in[k], acc);
        }
        out[j] = acc;
    }
}

template <int N>
__device__ __forceinline__ void swish_vec(float (&h)[N]) {
#pragma unroll
    for (int j = 0; j < N; ++j) h[j] = swish_f(h[j]);
}

__global__ __launch_bounds__(256, 4) void longnet_mlp_kernel(
    const float* __restrict__ x,
    const float* __restrict__ W0, const float* __restrict__ b0,
    const float* __restrict__ W1, const float* __restrict__ b1,
    const float* __restrict__ W2, const float* __restrict__ b2,
    const float* __restrict__ W3, const float* __restrict__ b3,
    const float* __restrict__ W4, const float* __restrict__ b4,
    const float* __restrict__ W5, const float* __restrict__ b5,
    const float* __restrict__ W6, const float* __restrict__ b6,
    const float* __restrict__ W7, const float* __restrict__ b7,
    const float* __restrict__ W8, const float* __restrict__ b8,
    const float* __restrict__ W9, const float* __restrict__ b9,
    float* __restrict__ out, int n) {
    const int row = blockIdx.x * blockDim.x + threadIdx.x;
    if (row >= n) return;

    float h0[11];
#pragma unroll
    for (int k = 0; k < 11; ++k) h0[k] = x[row * 11 + k];

    float h1[20];
    linear_layer<11, 20>(W0, b0, h0, h1);
    swish_vec(h1);
    float h2[20];
    linear_layer<20, 20>(W1, b1, h1, h2);
    swish_vec(h2);
    float h3[30];
    linear_layer<20, 30>(W2, b2, h2, h3);
    swish_vec(h3);
    float h4[30];
    linear_layer<30, 30>(W3, b3, h3, h4);
    swish_vec(h4);
    float h5[40];
    linear_layer<30, 40>(W4, b4, h4, h5);
    swish_vec(h5);
    float h6[40];
    linear_layer<40, 40>(W5, b5, h5, h6);
    swish_vec(h6);
    float h7[40];
    linear_layer<40, 40>(W6, b6, h6, h7);
    swish_vec(h7);
    float h8[20];
    linear_layer<40, 20>(W7, b7, h7, h8);
    swish_vec(h8);
    float h9[10];
    linear_layer<20, 10>(W8, b8, h8, h9);
    swish_vec(h9);
    float h10[1];
    linear_layer<10, 1>(W9, b9, h9, h10);

    out[row] = fmaxf(h10[0], 0.0f);
}

extern "C" void kernel_launch(void* const* d_in, const int* in_sizes, int n_in,
                              void* d_out, int out_size, void* d_ws, size_t ws_size,
                              hipStream_t stream) {
    const float* x = (const float*)d_in[0];
    const float* W0 = (const float*)d_in[1];
    const float* b0 = (const float*)d_in[2];
    const float* W1 = (const float*)d_in[3];
    const float* b1 = (const float*)d_in[4];
    const float* W2 = (const float*)d_in[5];
    const float* b2 = (const float*)d_in[6];
    const float* W3 = (const float*)d_in[7];
    const float* b3 = (const float*)d_in[8];
    const float* W4 = (const float*)d_in[9];
    const float* b4 = (const float*)d_in[10];
    const float* W5 = (const float*)d_in[11];
    const float* b5 = (const float*)d_in[12];
    const float* W6 = (const float*)d_in[13];
    const float* b6 = (const float*)d_in[14];
    const float* W7 = (const float*)d_in[15];
    const float* b7 = (const float*)d_in[16];
    const float* W8 = (const float*)d_in[17];
    const float* b8 = (const float*)d_in[18];
    const float* W9 = (const float*)d_in[19];
    const float* b9 = (const float*)d_in[20];
    float* out = (float*)d_out;

    const int n = in_sizes[0] / 11;  // 2,000,000 rows
    const int block = 256;
    const int grid = (n + block - 1) / block;

    longnet_mlp_kernel<<<grid, block, 0, stream>>>(
        x, W0, b0, W1, b1, W2, b2, W3, b3, W4, b4, W5, b5, W6, b6, W7, b7, W8,
        b8, W9, b9, out, n);
}

// Round 3
// 346.526 us; speedup vs baseline: 1.4240x; 1.4239x over previous
//
#include <hip/hip_runtime.h>
#include <math.h>

// 10-layer MLP over 2M rows via fp16 MFMA (fp32 accumulate).
// Layers padded: N-tiles of 16, K-tiles of 32. Per wave: 16-row activation
// tile in LDS (stride 72 f16 -> <=2-way bank conflicts); all weights staged
// f16 in LDS once per block (row pad +8 f16 -> <=2-way on B-frag reads).
// Per layer: all output-tile accs computed in registers (reads only), THEN
// epilogue (bias+swish+cvt) writes back to the same act buffer -> no WAR.
// MFMA floor ~15us; swish VALU floor ~70us (overlaps MFMA across waves).

typedef _Float16 half8 __attribute__((ext_vector_type(8)));
typedef float f32x4 __attribute__((ext_vector_type(4)));

#define ACT_W 72  // 64 + 8 pad, in f16 elements (144 B row stride)

__device__ __forceinline__ float swish_f(float a) {
    float e = __expf(-a);
    return a * __builtin_amdgcn_rcpf(1.0f + e);
}

// Stage one layer's weights (f32 global, [OUT][IN] row-major) into LDS f16,
// zero-padded to [OUT_P][IN_P], row stride IN_P+8.
template <int IN, int OUT, int IN_P, int OUT_P>
__device__ __forceinline__ void stage_w(const float* __restrict__ W,
                                        _Float16* dst, int tid) {
    const int STRIDE = IN_P + 8;
    for (int s = tid; s < OUT_P * IN_P; s += 256) {
        const int r = s / IN_P;  // IN_P is 32/64 -> shift
        const int c = s % IN_P;
        float v = (r < OUT && c < IN) ? W[r * IN + c] : 0.0f;
        dst[r * STRIDE + c] = (_Float16)v;
    }
}

template <int OUT, int OUT_P>
__device__ __forceinline__ void stage_b(const float* __restrict__ b,
                                        float* dst, int tid) {
    if (tid < OUT_P) dst[tid] = (tid < OUT) ? b[tid] : 0.0f;
}

// One layer: act[16][ACT_W] (f16) -> act (in place, write-after-all-reads).
// A-frag: row = lane&15, k = (lane>>4)*8 + e (contiguous 16B ds_read).
// B-frag: col = lane&15 (output feature), same k pattern, from W lds.
// D: col = lane&15, row = (lane>>4)*4 + reg  [m89-verified layout].
template <int IN_P, int OUT_P, int OUT, bool FINAL>
__device__ __forceinline__ void layer_fn(const _Float16* __restrict__ wl,
                                         const float* __restrict__ bl,
                                         _Float16* act,
                                         float* __restrict__ gout, int row0,
                                         int n, int lane) {
    const int lr = lane & 15;
    const int kg = lane >> 4;
    const int WSTRIDE = IN_P + 8;

    f32x4 acc[OUT_P / 16];
#pragma unroll
    for (int ot = 0; ot < OUT_P / 16; ++ot) {
        acc[ot] = (f32x4){0.0f, 0.0f, 0.0f, 0.0f};
#pragma unroll
        for (int kt = 0; kt < IN_P / 32; ++kt) {
            const int k0 = kt * 32 + kg * 8;
            half8 a = *(const half8*)(act + lr * ACT_W + k0);
            half8 b = *(const half8*)(wl + (ot * 16 + lr) * WSTRIDE + k0);
            acc[ot] = __builtin_amdgcn_mfma_f32_16x16x32_f16(a, b, acc[ot], 0, 0, 0);
        }
    }

#pragma unroll
    for (int ot = 0; ot < OUT_P / 16; ++ot) {
        const int j = ot * 16 + lr;
        const float bj = bl[j];
#pragma unroll
        for (int r = 0; r < 4; ++r) {
            const int row = kg * 4 + r;
            float v = acc[ot][r] + bj;
            if constexpr (FINAL) {
                if (j == 0) {
                    const int g = row0 + row;
                    if (g < n) gout[g] = fmaxf(v, 0.0f);
                }
            } else {
                _Float16 h;
                if (j < OUT)
                    h = (_Float16)swish_f(v);
                else
                    h = (_Float16)0.0f;
                act[row * ACT_W + j] = h;
            }
        }
    }
}

__global__ __launch_bounds__(256) void longnet_mlp_mfma(
    const float* __restrict__ x,
    const float* __restrict__ W0, const float* __restrict__ b0,
    const float* __restrict__ W1, const float* __restrict__ b1,
    const float* __restrict__ W2, const float* __restrict__ b2,
    const float* __restrict__ W3, const float* __restrict__ b3,
    const float* __restrict__ W4, const float* __restrict__ b4,
    const float* __restrict__ W5, const float* __restrict__ b5,
    const float* __restrict__ W6, const float* __restrict__ b6,
    const float* __restrict__ W7, const float* __restrict__ b7,
    const float* __restrict__ W8, const float* __restrict__ b8,
    const float* __restrict__ W9, const float* __restrict__ b9,
    float* __restrict__ out, int n) {
    // LDS: weights 18176 f16 (36352B) + bias 352 f32 (1408B) + 4 wave act
    // tiles 4*1152 f16 (9216B) = 46976 B -> 3 blocks/CU.
    __shared__ __align__(16) _Float16 s_w[18176];
    __shared__ __align__(16) float s_b[352];
    __shared__ __align__(16) _Float16 s_act[4][16 * ACT_W];

    const int tid = threadIdx.x;
    const int lane = tid & 63;
    const int wave = tid >> 6;

    // ---- stage weights/biases (whole block) ----
    stage_w<11, 20, 32, 32>(W0, s_w + 0, tid);
    stage_w<20, 20, 32, 32>(W1, s_w + 1280, tid);
    stage_w<20, 30, 32, 32>(W2, s_w + 2560, tid);
    stage_w<30, 30, 32, 32>(W3, s_w + 3840, tid);
    stage_w<30, 40, 32, 48>(W4, s_w + 5120, tid);
    stage_w<40, 40, 64, 48>(W5, s_w + 7040, tid);
    stage_w<40, 40, 64, 48>(W6, s_w + 10496, tid);
    stage_w<40, 20, 64, 32>(W7, s_w + 13952, tid);
    stage_w<20, 10, 32, 32>(W8, s_w + 16256, tid);
    stage_w<10, 1, 32, 16>(W9, s_w + 17536, tid);
    stage_b<20, 32>(b0, s_b + 0, tid);
    stage_b<20, 32>(b1, s_b + 32, tid);
    stage_b<30, 32>(b2, s_b + 64, tid);
    stage_b<30, 32>(b3, s_b + 96, tid);
    stage_b<40, 48>(b4, s_b + 128, tid);
    stage_b<40, 48>(b5, s_b + 176, tid);
    stage_b<40, 48>(b6, s_b + 224, tid);
    stage_b<20, 32>(b7, s_b + 272, tid);
    stage_b<10, 32>(b8, s_b + 304, tid);
    stage_b<1, 16>(b9, s_b + 336, tid);
    __syncthreads();

    _Float16* act = s_act[wave];

    // one-time zero of full act tile (288 dwords) -- cols 48..71 stay 0
    // forever (read as K-pad by the 64-wide layers, never written).
#pragma unroll
    for (int it = 0; it < 5; ++it) {
        const int idx = it * 64 + lane;
        if (idx < 288) ((int*)act)[idx] = 0;
    }

    const int block_row0 = blockIdx.x * 256;

    for (int t = 0; t < 4; ++t) {
        const int row0 = block_row0 + wave * 64 + t * 16;

        // x fill: 16 rows x 16 cols (cols 11..15 zero)
#pragma unroll
        for (int it = 0; it < 4; ++it) {
            const int slot = it * 64 + lane;
            const int r = slot >> 4;
            const int c = slot & 15;
            float v = 0.0f;
            const int g = row0 + r;
            if (c < 11 && g < n) v = x[g * 11 + c];
            act[r * ACT_W + c] = (_Float16)v;
        }
        // zero cols 16..31 (dwords 8..15 of each row); disjoint from x fill
#pragma unroll
        for (int it = 0; it < 2; ++it) {
            const int slot = it * 64 + lane;  // 128 slots
            const int r = slot >> 3;
            const int dw = 8 + (slot & 7);
            *(int*)(act + r * ACT_W + dw * 2) = 0;
        }

        layer_fn<32, 32, 20, false>(s_w + 0, s_b + 0, act, out, row0, n, lane);
        layer_fn<32, 32, 20, false>(s_w + 1280, s_b + 32, act, out, row0, n, lane);
        layer_fn<32, 32, 30, false>(s_w + 2560, s_b + 64, act, out, row0, n, lane);
        layer_fn<32, 32, 30, false>(s_w + 3840, s_b + 96, act, out, row0, n, lane);
        layer_fn<32, 48, 40, false>(s_w + 5120, s_b + 128, act, out, row0, n, lane);
        layer_fn<64, 48, 40, false>(s_w + 7040, s_b + 176, act, out, row0, n, lane);
        layer_fn<64, 48, 40, false>(s_w + 10496, s_b + 224, act, out, row0, n, lane);
        layer_fn<64, 32, 20, false>(s_w + 13952, s_b + 272, act, out, row0, n, lane);
        layer_fn<32, 32, 10, false>(s_w + 16256, s_b + 304, act, out, row0, n, lane);
        layer_fn<32, 16, 1, true>(s_w + 17536, s_b + 336, act, out, row0, n, lane);
    }
}

extern "C" void kernel_launch(void* const* d_in, const int* in_sizes, int n_in,
                              void* d_out, int out_size, void* d_ws, size_t ws_size,
                              hipStream_t stream) {
    const float* x = (const float*)d_in[0];
    const float* W0 = (const float*)d_in[1];
    const float* b0 = (const float*)d_in[2];
    const float* W1 = (const float*)d_in[3];
    const float* b1 = (const float*)d_in[4];
    const float* W2 = (const float*)d_in[5];
    const float* b2 = (const float*)d_in[6];
    const float* W3 = (const float*)d_in[7];
    const float* b3 = (const float*)d_in[8];
    const float* W4 = (const float*)d_in[9];
    const float* b4 = (const float*)d_in[10];
    const float* W5 = (const float*)d_in[11];
    const float* b5 = (const float*)d_in[12];
    const float* W6 = (const float*)d_in[13];
    const float* b6 = (const float*)d_in[14];
    const float* W7 = (const float*)d_in[15];
    const float* b7 = (const float*)d_in[16];
    const float* W8 = (const float*)d_in[17];
    const float* b8 = (const float*)d_in[18];
    const float* W9 = (const float*)d_in[19];
    const float* b9 = (const float*)d_in[20];
    float* out = (float*)d_out;

    const int n = in_sizes[0] / 11;  // 2,000,000 rows
    const int rows_per_block = 256;  // 4 waves x 4 tiles x 16 rows
    const int grid = (n + rows_per_block - 1) / rows_per_block;

    longnet_mlp_mfma<<<grid, 256, 0, stream>>>(
        x, W0, b0, W1, b1, W2, b2, W3, b3, W4, b4, W5, b5, W6, b6, W7, b7, W8,
        b8, W9, b9, out, n);
}

// Round 4
// 271.281 us; speedup vs baseline: 1.8189x; 1.2774x over previous
//
#include <hip/hip_runtime.h>
#include <math.h>

// 10-layer MLP, fp16 MFMA (fp32 acc), 16-row tiles, grid-stride per wave.
// R4: weights+biases live in VGPRs (30 half8 frags, loaded once per wave);
// operand-swapped MFMA (D^T: col=sample, row=feature) so epilogue packs
// 4 consecutive features -> one ds_write_b64; bias folded in as an extra
// K-column (activation marker 1.0 at feature==OUT, weight col k==IN=bias);
// layer-0 operand comes straight from global x. No barriers, LDS = act only.

typedef _Float16 half8 __attribute__((ext_vector_type(8)));
typedef _Float16 half4 __attribute__((ext_vector_type(4)));
typedef float f32x4 __attribute__((ext_vector_type(4)));

#define ACT_W 72  // act row stride in f16 (144 B = 9*16B: b128-aligned, ~2-way banks)

__device__ __forceinline__ float swish_f(float a) {
    float e = __expf(-a);
    return a * __builtin_amdgcn_rcpf(1.0f + e);
}

// Load one layer's weight fragments into registers.
// A-frag layout (validated R3): row = lane&15 (= output feature ot*16+lr),
// k = (lane>>4)*8 + e. Column k==IN holds the bias (augmented-K trick);
// rows >= OUT and columns > IN are zero.
template <int IN, int OUT, int IN_P, int OUT_P>
__device__ __forceinline__ void load_wf(const float* __restrict__ W,
                                        const float* __restrict__ b,
                                        half8 (&wf)[OUT_P / 16][IN_P / 32],
                                        int lr, int kg) {
#pragma unroll
    for (int ot = 0; ot < OUT_P / 16; ++ot) {
        const int r = ot * 16 + lr;
#pragma unroll
        for (int kt = 0; kt < IN_P / 32; ++kt) {
            half8 h;
#pragma unroll
            for (int e = 0; e < 8; ++e) {
                const int k = kt * 32 + kg * 8 + e;
                float v = 0.0f;
                if (r < OUT) {
                    if (k < IN)
                        v = W[r * IN + k];
                    else if (k == IN)
                        v = b[r];
                }
                h[e] = (_Float16)v;
            }
            wf[ot][kt] = h;
        }
    }
}

// Epilogue: acc[ot][r] = feature ot*16+kg4+r of sample lane&15 (D^T layout).
// swish everything (pad features have acc==0 -> swish 0), then overwrite the
// feature==OUT slot with the 1.0 bias-marker for the next layer, pack 4
// features -> b64 store.
template <int NOT, int OUT>
__device__ __forceinline__ void epilogue(const f32x4 (&acc)[NOT],
                                         _Float16* wrp, int kg4) {
#pragma unroll
    for (int ot = 0; ot < NOT; ++ot) {
        float v[4];
#pragma unroll
        for (int r = 0; r < 4; ++r) {
            v[r] = swish_f(acc[ot][r]);
            if (ot == OUT / 16) {  // compile-time pruned per ot
                if (ot * 16 + kg4 + r == OUT) v[r] = 1.0f;
            }
        }
        half4 h = {(_Float16)v[0], (_Float16)v[1], (_Float16)v[2],
                   (_Float16)v[3]};
        *(half4*)(wrp + ot * 16) = h;
    }
}

template <int NOT, int NKT, int OUT>
__device__ __forceinline__ void layer_lds(const half8 (&wf)[NOT][NKT],
                                          const _Float16* rdp, _Float16* wrp,
                                          int kg4) {
    f32x4 acc[NOT];
#pragma unroll
    for (int ot = 0; ot < NOT; ++ot) acc[ot] = (f32x4){0.f, 0.f, 0.f, 0.f};
#pragma unroll
    for (int kt = 0; kt < NKT; ++kt) {
        const half8 bf = *(const half8*)(rdp + kt * 32);
#pragma unroll
        for (int ot = 0; ot < NOT; ++ot)
            acc[ot] = __builtin_amdgcn_mfma_f32_16x16x32_f16(wf[ot][kt], bf,
                                                             acc[ot], 0, 0, 0);
    }
    epilogue<NOT, OUT>(acc, wrp, kg4);
}

template <int NOT, int OUT>
__device__ __forceinline__ void layer_first(const half8 (&wf)[NOT][1],
                                            half8 bf, _Float16* wrp, int kg4) {
    f32x4 acc[NOT];
#pragma unroll
    for (int ot = 0; ot < NOT; ++ot) {
        acc[ot] = (f32x4){0.f, 0.f, 0.f, 0.f};
        acc[ot] = __builtin_amdgcn_mfma_f32_16x16x32_f16(wf[ot][0], bf,
                                                         acc[ot], 0, 0, 0);
    }
    epilogue<NOT, OUT>(acc, wrp, kg4);
}

__global__ __launch_bounds__(256, 2) void longnet_mlp_r4(
    const float* __restrict__ x,
    const float* __restrict__ W0, const float* __restrict__ b0,
    const float* __restrict__ W1, const float* __restrict__ b1,
    const float* __restrict__ W2, const float* __restrict__ b2,
    const float* __restrict__ W3, const float* __restrict__ b3,
    const float* __restrict__ W4, const float* __restrict__ b4,
    const float* __restrict__ W5, const float* __restrict__ b5,
    const float* __restrict__ W6, const float* __restrict__ b6,
    const float* __restrict__ W7, const float* __restrict__ b7,
    const float* __restrict__ W8, const float* __restrict__ b8,
    const float* __restrict__ W9, const float* __restrict__ b9,
    float* __restrict__ out, int n) {
    __shared__ __align__(16) _Float16 s_act[4][16 * ACT_W];

    const int tid = threadIdx.x;
    const int lane = tid & 63;
    const int wave = tid >> 6;
    const int lr = lane & 15;
    const int kg = lane >> 4;
    const int kg4 = kg * 4;

    // ---- all weights + biases into VGPRs (once per wave) ----
    half8 w0[2][1]; load_wf<11, 20, 32, 32>(W0, b0, w0, lr, kg);
    half8 w1[2][1]; load_wf<20, 20, 32, 32>(W1, b1, w1, lr, kg);
    half8 w2[2][1]; load_wf<20, 30, 32, 32>(W2, b2, w2, lr, kg);
    half8 w3[2][1]; load_wf<30, 30, 32, 32>(W3, b3, w3, lr, kg);
    half8 w4[3][1]; load_wf<30, 40, 32, 48>(W4, b4, w4, lr, kg);
    half8 w5[3][2]; load_wf<40, 40, 64, 48>(W5, b5, w5, lr, kg);
    half8 w6[3][2]; load_wf<40, 40, 64, 48>(W6, b6, w6, lr, kg);
    half8 w7[2][2]; load_wf<40, 20, 64, 32>(W7, b7, w7, lr, kg);
    half8 w8[2][1]; load_wf<20, 10, 32, 32>(W8, b8, w8, lr, kg);
    half8 w9[1][1]; load_wf<10, 1, 32, 16>(W9, b9, w9, lr, kg);

    _Float16* act = s_act[wave];
    // zero the wave's act tile once; cols 48..63 stay zero forever (K-pad
    // for the 64-wide layers; OUT_P never exceeds 48).
    {
        int* a32 = (int*)act;
#pragma unroll
        for (int i = 0; i < 9; ++i) a32[i * 64 + lane] = 0;  // 576 dwords
    }

    const _Float16* rdp = act + lr * ACT_W + kg * 8;  // B-frag read base
    _Float16* wrp = act + lr * ACT_W + kg4;           // epilogue write base

    const int ntile = n >> 4;  // n = 2e6, divisible by 16
    const int step = (int)gridDim.x * 4;

    for (int t = blockIdx.x * 4 + wave; t < ntile; t += step) {
        const int row0 = t * 16;

        // layer-0 B-frag straight from global x: col=sample(lr),
        // k=kg*8+e = input feature; feature 11 = 1.0 bias marker.
        half8 xb = {};
        if (kg < 2) {
            const float* xr = x + (size_t)(row0 + lr) * 11 + kg * 8;
#pragma unroll
            for (int e = 0; e < 8; ++e) {
                const int k = kg * 8 + e;
                float v = (k < 11) ? xr[e] : ((k == 11) ? 1.0f : 0.0f);
                xb[e] = (_Float16)v;
            }
        }

        layer_first<2, 20>(w0, xb, wrp, kg4);
        layer_lds<2, 1, 20>(w1, rdp, wrp, kg4);
        layer_lds<2, 1, 30>(w2, rdp, wrp, kg4);
        layer_lds<2, 1, 30>(w3, rdp, wrp, kg4);
        layer_lds<3, 1, 40>(w4, rdp, wrp, kg4);
        layer_lds<3, 2, 40>(w5, rdp, wrp, kg4);
        layer_lds<3, 2, 40>(w6, rdp, wrp, kg4);
        layer_lds<2, 2, 20>(w7, rdp, wrp, kg4);
        layer_lds<2, 1, 10>(w8, rdp, wrp, kg4);

        // final layer 10->1 (+ReLU): only feature 0 (kg==0, r==0) is real.
        f32x4 accF = (f32x4){0.f, 0.f, 0.f, 0.f};
        {
            const half8 bf = *(const half8*)rdp;
            accF = __builtin_amdgcn_mfma_f32_16x16x32_f16(w9[0][0], bf, accF,
                                                          0, 0, 0);
        }
        if (kg == 0) out[row0 + lr] = fmaxf(accF[0], 0.0f);
    }
}

extern "C" void kernel_launch(void* const* d_in, const int* in_sizes, int n_in,
                              void* d_out, int out_size, void* d_ws, size_t ws_size,
                              hipStream_t stream) {
    const float* x = (const float*)d_in[0];
    const float* W0 = (const float*)d_in[1];
    const float* b0 = (const float*)d_in[2];
    const float* W1 = (const float*)d_in[3];
    const float* b1 = (const float*)d_in[4];
    const float* W2 = (const float*)d_in[5];
    const float* b2 = (const float*)d_in[6];
    const float* W3 = (const float*)d_in[7];
    const float* b3 = (const float*)d_in[8];
    const float* W4 = (const float*)d_in[9];
    const float* b4 = (const float*)d_in[10];
    const float* W5 = (const float*)d_in[11];
    const float* b5 = (const float*)d_in[12];
    const float* W6 = (const float*)d_in[13];
    const float* b6 = (const float*)d_in[14];
    const float* W7 = (const float*)d_in[15];
    const float* b7 = (const float*)d_in[16];
    const float* W8 = (const float*)d_in[17];
    const float* b8 = (const float*)d_in[18];
    const float* W9 = (const float*)d_in[19];
    const float* b9 = (const float*)d_in[20];
    float* out = (float*)d_out;

    const int n = in_sizes[0] / 11;  // 2,000,000 rows
    const int grid = 2048;           // grid-stride; ~15 tiles/wave

    longnet_mlp_r4<<<grid, 256, 0, stream>>>(
        x, W0, b0, W1, b1, W2, b2, W3, b3, W4, b4, W5, b5, W6, b6, W7, b7, W8,
        b8, W9, b9, out, n);
}

// Round 5
// 200.130 us; speedup vs baseline: 2.4656x; 1.3555x over previous
//
#include <hip/hip_runtime.h>
#include <math.h>

// 10-layer MLP, fp16 MFMA (fp32 acc), 16-row tiles, grid-stride per wave.
// R5: weights live in LDS in FRAGMENT-PACKED order (29 frags x 1KB; read
// ds_read_b128 at frag*1024+lane*16 -> zero bank conflicts), staged once per
// persistent block. Frees ~120 weight-VGPRs -> 4 blocks/CU (50% occupancy)
// to hide LDS round-trip + transcendental latency. Epilogue uses cvt_pkrtz.
// Bias folded as augmented-K column (marker 1.0 at feature==OUT).

typedef _Float16 half8 __attribute__((ext_vector_type(8)));
typedef _Float16 half4 __attribute__((ext_vector_type(4)));
typedef _Float16 half2 __attribute__((ext_vector_type(2)));
typedef float f32x4 __attribute__((ext_vector_type(4)));

#define ACT_W 72  // act row stride in f16 (144 B = 9*16B, 2-way banks = free)

__device__ __forceinline__ float swish_f(float a) {
    float e = __expf(-a);
    return a * __builtin_amdgcn_rcpf(1.0f + e);
}

// One lane's 8 f16 of weight fragment (ot,kt): A-frag layout row=ot*16+lr,
// k=kt*32+kg*8+e. Column k==IN holds the bias (augmented-K); else zero-pad.
__device__ __forceinline__ half8 make_frag(const float* __restrict__ W,
                                           const float* __restrict__ b,
                                           int IN, int OUT, int ot, int kt,
                                           int lr, int kg) {
    const int r = ot * 16 + lr;
    half8 h;
#pragma unroll
    for (int e = 0; e < 8; ++e) {
        const int k = kt * 32 + kg * 8 + e;
        float v = 0.0f;
        if (r < OUT) {
            if (k < IN)
                v = W[r * IN + k];
            else if (k == IN)
                v = b[r];
        }
        h[e] = (_Float16)v;
    }
    return h;
}

// acc[ot][r] = feature ot*16+kg4+r of sample lane&15 (D^T). Swish all (pad
// accs are 0 -> swish 0), overwrite feature==OUT with 1.0 marker, pack via
// cvt_pkrtz, one b64 store per group.
template <int NOT, int OUT>
__device__ __forceinline__ void epilogue(const f32x4 (&acc)[NOT],
                                         _Float16* wrp, int kg4) {
#pragma unroll
    for (int ot = 0; ot < NOT; ++ot) {
        float v[4];
#pragma unroll
        for (int r = 0; r < 4; ++r) {
            v[r] = swish_f(acc[ot][r]);
            if (ot == OUT / 16 && ot * 16 + kg4 + r == OUT) v[r] = 1.0f;
        }
        auto lo = __builtin_amdgcn_cvt_pkrtz(v[0], v[1]);
        auto hi = __builtin_amdgcn_cvt_pkrtz(v[2], v[3]);
        union {
            half4 h4;
            half2 h2[2];
        } u;
        u.h2[0] = __builtin_bit_cast(half2, lo);
        u.h2[1] = __builtin_bit_cast(half2, hi);
        *(half4*)(wrp + ot * 16) = u.h4;
    }
}

// One layer; weight frags from LDS (wb = s_w + fragbase*512, frag (ot,kt) at
// (ot*NKT+kt)*512 + lane*8 -> linear conflict-free ds_read_b128).
template <int NOT, int NKT, int OUT>
__device__ __forceinline__ void layer(const _Float16* __restrict__ wb,
                                      const _Float16* rdp, _Float16* wrp,
                                      int lane, int kg4) {
    f32x4 acc[NOT];
#pragma unroll
    for (int ot = 0; ot < NOT; ++ot) acc[ot] = (f32x4){0.f, 0.f, 0.f, 0.f};
#pragma unroll
    for (int kt = 0; kt < NKT; ++kt) {
        const half8 bf = *(const half8*)(rdp + kt * 32);
#pragma unroll
        for (int ot = 0; ot < NOT; ++ot) {
            const half8 wf =
                *(const half8*)(wb + (ot * NKT + kt) * 512 + lane * 8);
            acc[ot] = __builtin_amdgcn_mfma_f32_16x16x32_f16(wf, bf, acc[ot],
                                                             0, 0, 0);
        }
    }
    epilogue<NOT, OUT>(acc, wrp, kg4);
}

__global__ __launch_bounds__(256, 4) void longnet_mlp_r5(
    const float* __restrict__ x,
    const float* __restrict__ W0, const float* __restrict__ b0,
    const float* __restrict__ W1, const float* __restrict__ b1,
    const float* __restrict__ W2, const float* __restrict__ b2,
    const float* __restrict__ W3, const float* __restrict__ b3,
    const float* __restrict__ W4, const float* __restrict__ b4,
    const float* __restrict__ W5, const float* __restrict__ b5,
    const float* __restrict__ W6, const float* __restrict__ b6,
    const float* __restrict__ W7, const float* __restrict__ b7,
    const float* __restrict__ W8, const float* __restrict__ b8,
    const float* __restrict__ W9, const float* __restrict__ b9,
    float* __restrict__ out, int n) {
    // 29 frags x 512 f16 = 29696 B weights + 4 x 1152 f16 act = 9216 B
    // -> 38912 B total -> 4 blocks/CU.
    __shared__ __align__(16) _Float16 s_w[29 * 512];
    __shared__ __align__(16) _Float16 s_act[4][16 * ACT_W];

    const int tid = threadIdx.x;
    const int lane = tid & 63;
    const int wave = tid >> 6;
    const int lr = lane & 15;
    const int kg = lane >> 4;
    const int kg4 = kg * 4;

    // ---- stage 29 weight frags into LDS (waves split round-robin) ----
    {
        const float* Wt[10] = {W0, W1, W2, W3, W4, W5, W6, W7, W8, W9};
        const float* bt[10] = {b0, b1, b2, b3, b4, b5, b6, b7, b8, b9};
        const int INs[10] = {11, 20, 20, 30, 30, 40, 40, 40, 20, 10};
        const int OUTs[10] = {20, 20, 30, 30, 40, 40, 40, 20, 10, 1};
        const int NOTs[10] = {2, 2, 2, 2, 3, 3, 3, 2, 1, 1};
        const int NKTs[10] = {1, 1, 1, 1, 1, 2, 2, 2, 1, 1};
        int f = 0;
        for (int L = 0; L < 10; ++L)
            for (int ot = 0; ot < NOTs[L]; ++ot)
                for (int kt = 0; kt < NKTs[L]; ++kt, ++f)
                    if ((f & 3) == wave) {
                        half8 h = make_frag(Wt[L], bt[L], INs[L], OUTs[L], ot,
                                            kt, lr, kg);
                        *(half8*)(s_w + f * 512 + lane * 8) = h;
                    }
    }

    _Float16* act = s_act[wave];
    // zero wave's act tile once; cols 48..63 stay zero forever (K-pad).
    {
        int* a32 = (int*)act;
#pragma unroll
        for (int i = 0; i < 9; ++i) a32[i * 64 + lane] = 0;
    }
    __syncthreads();

    const _Float16* rdp = act + lr * ACT_W + kg * 8;  // B-frag read base
    _Float16* wrp = act + lr * ACT_W + kg4;           // epilogue write base

    const int ntile = n >> 4;  // n = 2e6, divisible by 16
    const int step = (int)gridDim.x * 4;

    for (int t = blockIdx.x * 4 + wave; t < ntile; t += step) {
        const int row0 = t * 16;

        // layer-0 B-frag straight from global x: col=sample(lr), k=feature;
        // feature 11 = 1.0 bias marker. kg>=2 lanes are all K-pad (zero).
        half8 xb = {};
        if (kg < 2) {
            const float* xr = x + (size_t)(row0 + lr) * 11 + kg * 8;
#pragma unroll
            for (int e = 0; e < 8; ++e) {
                const int k = kg * 8 + e;
                float v = (k < 11) ? xr[e] : ((k == 11) ? 1.0f : 0.0f);
                xb[e] = (_Float16)v;
            }
        }

        // layer 0 from registers (x), rest from LDS act.
        {
            f32x4 acc[2];
#pragma unroll
            for (int ot = 0; ot < 2; ++ot) {
                const half8 wf = *(const half8*)(s_w + ot * 512 + lane * 8);
                acc[ot] = (f32x4){0.f, 0.f, 0.f, 0.f};
                acc[ot] = __builtin_amdgcn_mfma_f32_16x16x32_f16(wf, xb,
                                                                 acc[ot], 0,
                                                                 0, 0);
            }
            epilogue<2, 20>(acc, wrp, kg4);
        }
        layer<2, 1, 20>(s_w + 2 * 512, rdp, wrp, lane, kg4);
        layer<2, 1, 30>(s_w + 4 * 512, rdp, wrp, lane, kg4);
        layer<2, 1, 30>(s_w + 6 * 512, rdp, wrp, lane, kg4);
        layer<3, 1, 40>(s_w + 8 * 512, rdp, wrp, lane, kg4);
        layer<3, 2, 40>(s_w + 11 * 512, rdp, wrp, lane, kg4);
        layer<3, 2, 40>(s_w + 17 * 512, rdp, wrp, lane, kg4);
        layer<2, 2, 20>(s_w + 23 * 512, rdp, wrp, lane, kg4);
        // L8 (20->10): only ot=0 written; stale features 16..31 are killed
        // by w9's zero columns.
        layer<1, 1, 10>(s_w + 27 * 512, rdp, wrp, lane, kg4);

        // final layer 10->1 (+ReLU): feature 0 lives in kg==0, reg 0.
        {
            const half8 wf = *(const half8*)(s_w + 28 * 512 + lane * 8);
            const half8 bf = *(const half8*)rdp;
            f32x4 accF = (f32x4){0.f, 0.f, 0.f, 0.f};
            accF =
                __builtin_amdgcn_mfma_f32_16x16x32_f16(wf, bf, accF, 0, 0, 0);
            if (kg == 0) out[row0 + lr] = fmaxf(accF[0], 0.0f);
        }
    }
}

extern "C" void kernel_launch(void* const* d_in, const int* in_sizes, int n_in,
                              void* d_out, int out_size, void* d_ws, size_t ws_size,
                              hipStream_t stream) {
    const float* x = (const float*)d_in[0];
    const float* W0 = (const float*)d_in[1];
    const float* b0 = (const float*)d_in[2];
    const float* W1 = (const float*)d_in[3];
    const float* b1 = (const float*)d_in[4];
    const float* W2 = (const float*)d_in[5];
    const float* b2 = (const float*)d_in[6];
    const float* W3 = (const float*)d_in[7];
    const float* b3 = (const float*)d_in[8];
    const float* W4 = (const float*)d_in[9];
    const float* b4 = (const float*)d_in[10];
    const float* W5 = (const float*)d_in[11];
    const float* b5 = (const float*)d_in[12];
    const float* W6 = (const float*)d_in[13];
    const float* b6 = (const float*)d_in[14];
    const float* W7 = (const float*)d_in[15];
    const float* b7 = (const float*)d_in[16];
    const float* W8 = (const float*)d_in[17];
    const float* b8 = (const float*)d_in[18];
    const float* W9 = (const float*)d_in[19];
    const float* b9 = (const float*)d_in[20];
    float* out = (float*)d_out;

    const int n = in_sizes[0] / 11;  // 2,000,000 rows
    const int grid = 1024;           // 4 blocks/CU resident, persistent

    longnet_mlp_r5<<<grid, 256, 0, stream>>>(
        x, W0, b0, W1, b1, W2, b2, W3, b3, W4, b4, W5, b5, W6, b6, W7, b7, W8,
        b8, W9, b9, out, n);
}